// Round 1
// baseline (1043.176 us; speedup 1.0000x reference)
//
#include <hip/hip_runtime.h>

#define N_NODES 20000
#define N_EDGES 320000
#define N_REL   100
#define FDIM    256
#define NHEAD   8
#define HDIM    32
#define NF      (N_NODES * FDIM)   // 5,120,000

// ---------------------------------------------------------------------------
// LayerNorm over 256 features, one wave (64 threads) per row, float4 per lane.
// ---------------------------------------------------------------------------
__global__ __launch_bounds__(64) void ln_kernel(
    const float* __restrict__ in, const float* __restrict__ g,
    const float* __restrict__ b, float* __restrict__ out, int rows)
{
    int row = blockIdx.x;
    if (row >= rows) return;
    int tid = threadIdx.x;
    const float4 v = *(const float4*)(in + (size_t)row * FDIM + tid * 4);
    float s = v.x + v.y + v.z + v.w;
    float q = v.x * v.x + v.y * v.y + v.z * v.z + v.w * v.w;
    #pragma unroll
    for (int d = 1; d < 64; d <<= 1) { s += __shfl_xor(s, d); q += __shfl_xor(q, d); }
    float mean = s * (1.0f / FDIM);
    float var  = q * (1.0f / FDIM) - mean * mean;
    float inv  = rsqrtf(var + 1e-5f);
    float4 gg = *(const float4*)(g + tid * 4);
    float4 bb = *(const float4*)(b + tid * 4);
    float4 o;
    o.x = (v.x - mean) * inv * gg.x + bb.x;
    o.y = (v.y - mean) * inv * gg.y + bb.y;
    o.z = (v.z - mean) * inv * gg.z + bb.z;
    o.w = (v.w - mean) * inv * gg.w + bb.w;
    *(float4*)(out + (size_t)row * FDIM + tid * 4) = o;
}

// rst = feat + ent ; y = LN(rst)
__global__ __launch_bounds__(64) void rst_ln_kernel(
    const float* __restrict__ feat, const float* __restrict__ ent,
    const float* __restrict__ g, const float* __restrict__ b,
    float* __restrict__ rst, float* __restrict__ y)
{
    int row = blockIdx.x;
    int tid = threadIdx.x;
    const float4 f = *(const float4*)(feat + (size_t)row * FDIM + tid * 4);
    const float4 e = *(const float4*)(ent  + (size_t)row * FDIM + tid * 4);
    float4 r;
    r.x = f.x + e.x; r.y = f.y + e.y; r.z = f.z + e.z; r.w = f.w + e.w;
    *(float4*)(rst + (size_t)row * FDIM + tid * 4) = r;
    float s = r.x + r.y + r.z + r.w;
    float q = r.x * r.x + r.y * r.y + r.z * r.z + r.w * r.w;
    #pragma unroll
    for (int d = 1; d < 64; d <<= 1) { s += __shfl_xor(s, d); q += __shfl_xor(q, d); }
    float mean = s * (1.0f / FDIM);
    float var  = q * (1.0f / FDIM) - mean * mean;
    float inv  = rsqrtf(var + 1e-5f);
    float4 gg = *(const float4*)(g + tid * 4);
    float4 bb = *(const float4*)(b + tid * 4);
    float4 o;
    o.x = (r.x - mean) * inv * gg.x + bb.x;
    o.y = (r.y - mean) * inv * gg.y + bb.y;
    o.z = (r.z - mean) * inv * gg.z + bb.z;
    o.w = (r.w - mean) * inv * gg.w + bb.w;
    *(float4*)(y + (size_t)row * FDIM + tid * 4) = o;
}

// ---------------------------------------------------------------------------
// FP32 tiled GEMM: C[M,N] = A[M,K] @ B[K,N] (+bias) (relu?) (+add)
// 64x64 tile, 256 threads, 4x4 microtile, TK=16.
// ---------------------------------------------------------------------------
__global__ __launch_bounds__(256) void gemm_kernel(
    const float* __restrict__ A, const float* __restrict__ B,
    const float* __restrict__ bias, const float* __restrict__ add,
    float* __restrict__ C, int M, int K, int N, int do_relu)
{
    __shared__ float As[16][64 + 4];   // transposed A tile; +4 keeps rows 16B-aligned
    __shared__ float Bs[16][64];
    int tid = threadIdx.x;
    int tx = tid & 15, ty = tid >> 4;
    int row0 = blockIdx.x * 64;
    int col0 = blockIdx.y * 64;
    float acc[4][4] = {};
    for (int k0 = 0; k0 < K; k0 += 16) {
        {   // A tile: thread -> float4 at (m = tid/4, kk = (tid&3)*4)
            int m  = tid >> 2;
            int kk = (tid & 3) * 4;
            int gr = row0 + m;
            float4 v = make_float4(0.f, 0.f, 0.f, 0.f);
            if (gr < M) v = *(const float4*)(A + (size_t)gr * K + k0 + kk);
            As[kk + 0][m] = v.x; As[kk + 1][m] = v.y;
            As[kk + 2][m] = v.z; As[kk + 3][m] = v.w;
        }
        {   // B tile: thread -> float4 at (kk = tid/16, c = (tid&15)*4)
            int kk = tid >> 4;
            int c4 = (tid & 15) * 4;
            *(float4*)&Bs[kk][c4] = *(const float4*)(B + (size_t)(k0 + kk) * N + col0 + c4);
        }
        __syncthreads();
        #pragma unroll
        for (int kk = 0; kk < 16; ++kk) {
            float4 a4 = *(const float4*)&As[kk][ty * 4];
            float4 b4 = *(const float4*)&Bs[kk][tx * 4];
            float av[4] = {a4.x, a4.y, a4.z, a4.w};
            float bv[4] = {b4.x, b4.y, b4.z, b4.w};
            #pragma unroll
            for (int i = 0; i < 4; ++i)
                #pragma unroll
                for (int j = 0; j < 4; ++j)
                    acc[i][j] += av[i] * bv[j];
        }
        __syncthreads();
    }
    int gc = col0 + tx * 4;
    #pragma unroll
    for (int i = 0; i < 4; ++i) {
        int gr = row0 + ty * 4 + i;
        if (gr >= M) break;
        float4 v = make_float4(acc[i][0], acc[i][1], acc[i][2], acc[i][3]);
        if (bias) {
            float4 bb = *(const float4*)(bias + gc);
            v.x += bb.x; v.y += bb.y; v.z += bb.z; v.w += bb.w;
        }
        if (do_relu) {
            v.x = fmaxf(v.x, 0.f); v.y = fmaxf(v.y, 0.f);
            v.z = fmaxf(v.z, 0.f); v.w = fmaxf(v.w, 0.f);
        }
        if (add) {
            float4 aa = *(const float4*)(add + (size_t)gr * N + gc);
            v.x += aa.x; v.y += aa.y; v.z += aa.z; v.w += aa.w;
        }
        *(float4*)(C + (size_t)gr * N + gc) = v;
    }
}

// ---------------------------------------------------------------------------
// Graph plumbing: degree count -> scan (offsets/cursor/logdeg) -> scatter CSR
// ---------------------------------------------------------------------------
__global__ void count_kernel(const int* __restrict__ dst, int* __restrict__ deg, int E)
{
    int i = blockIdx.x * blockDim.x + threadIdx.x;
    if (i < E) atomicAdd(&deg[dst[i]], 1);
}

__global__ __launch_bounds__(256) void scan_kernel(
    const int* __restrict__ deg, int* __restrict__ offsets, int* __restrict__ cursor,
    float* __restrict__ logdeg, int n)
{
    __shared__ int part[256];
    int tid = threadIdx.x;
    int chunk = (n + 255) / 256;
    int lo = tid * chunk;
    int hi = min(lo + chunk, n);
    int s = 0;
    for (int i = lo; i < hi; ++i) s += deg[i];
    part[tid] = s;
    __syncthreads();
    for (int d = 1; d < 256; d <<= 1) {
        int v = part[tid];
        int u = (tid >= d) ? part[tid - d] : 0;
        __syncthreads();
        part[tid] = v + u;
        __syncthreads();
    }
    int run = (tid == 0) ? 0 : part[tid - 1];
    for (int i = lo; i < hi; ++i) {
        offsets[i] = run;
        cursor[i]  = run;
        int d = deg[i];
        logdeg[i] = logf((float)d);
        run += d;
    }
    if (tid == 255) offsets[n] = run;
}

__global__ void scatter_kernel(const int* __restrict__ dst, int* __restrict__ cursor,
                               int* __restrict__ eorder, int E)
{
    int i = blockIdx.x * blockDim.x + threadIdx.x;
    if (i < E) {
        int p = atomicAdd(&cursor[dst[i]], 1);
        eorder[p] = i;
    }
}

// ---------------------------------------------------------------------------
// Edge attention score. 4 edges per 256-thread block (1 wave per edge).
// ex = exp(sum_d lrelu(fh*ftl*fr)*attn * logdeg[dst]/32); denom += ex.
// (segment-max subtraction skipped: softmax is invariant to it and |e| is
//  far below fp32 exp overflow here.)
// ---------------------------------------------------------------------------
__global__ __launch_bounds__(256) void edge_score_kernel(
    const float* __restrict__ fh, const float* __restrict__ ftl,
    const float* __restrict__ frel, const float* __restrict__ attn,
    const int* __restrict__ src, const int* __restrict__ dst,
    const int* __restrict__ rid, const float* __restrict__ logdeg,
    float* __restrict__ exbuf, float* __restrict__ denom, int E)
{
    int e = blockIdx.x * 4 + (threadIdx.x >> 6);
    if (e >= E) return;
    int tid = threadIdx.x & 63;
    int s = src[e], t = dst[e], r = rid[e];
    const float4 a4 = *(const float4*)(attn + tid * 4);
    const float4 hv = *(const float4*)(fh  + (size_t)s * FDIM + tid * 4);
    const float4 tv = *(const float4*)(ftl + (size_t)t * FDIM + tid * 4);
    const float4 rv = *(const float4*)(frel + (size_t)r * FDIM + tid * 4);
    float sum = 0.f, p;
    p = hv.x * tv.x * rv.x; p = (p > 0.f) ? p : 0.2f * p; sum += p * a4.x;
    p = hv.y * tv.y * rv.y; p = (p > 0.f) ? p : 0.2f * p; sum += p * a4.y;
    p = hv.z * tv.z * rv.z; p = (p > 0.f) ? p : 0.2f * p; sum += p * a4.z;
    p = hv.w * tv.w * rv.w; p = (p > 0.f) ? p : 0.2f * p; sum += p * a4.w;
    sum += __shfl_xor(sum, 1);
    sum += __shfl_xor(sum, 2);
    sum += __shfl_xor(sum, 4);
    if ((tid & 7) == 0) {
        int h = tid >> 3;
        float escore = sum * logdeg[t] * (1.0f / 32.0f);
        float ex = expf(escore);
        exbuf[(size_t)e * NHEAD + h] = ex;
        atomicAdd(&denom[(size_t)t * NHEAD + h], ex);
    }
}

__global__ void norm_kernel(float* __restrict__ a, const float* __restrict__ denom,
                            const int* __restrict__ dst, int E8)
{
    int i = blockIdx.x * blockDim.x + threadIdx.x;
    if (i < E8) {
        int e = i >> 3;
        a[i] = a[i] / denom[(size_t)dst[e] * NHEAD + (i & 7)];
    }
}

// ---------------------------------------------------------------------------
// One PPR hop, gather form (no atomics): fout[n] = 0.9*sum_in a*fin[src] + 0.1*feat0[n]
// One wave per node.
// ---------------------------------------------------------------------------
__global__ __launch_bounds__(64) void diffuse_kernel(
    const float* __restrict__ fin, const float* __restrict__ feat0,
    const float* __restrict__ a, const int* __restrict__ offsets,
    const int* __restrict__ eorder, const int* __restrict__ src,
    float* __restrict__ fout)
{
    int node = blockIdx.x;
    int tid = threadIdx.x;
    int h = tid >> 3;                   // element i = tid*4 -> head = tid/8
    int start = offsets[node], end = offsets[node + 1];
    float4 acc = make_float4(0.f, 0.f, 0.f, 0.f);
    for (int pcur = start; pcur < end; ++pcur) {
        int e = eorder[pcur];
        int s = src[e];
        float w = a[(size_t)e * NHEAD + h];
        const float4 f = *(const float4*)(fin + (size_t)s * FDIM + tid * 4);
        acc.x += w * f.x; acc.y += w * f.y; acc.z += w * f.z; acc.w += w * f.w;
    }
    const float4 f0 = *(const float4*)(feat0 + (size_t)node * FDIM + tid * 4);
    float4 o;
    o.x = 0.9f * acc.x + 0.1f * f0.x;
    o.y = 0.9f * acc.y + 0.1f * f0.y;
    o.z = 0.9f * acc.z + 0.1f * f0.z;
    o.w = 0.9f * acc.w + 0.1f * f0.w;
    *(float4*)(fout + (size_t)node * FDIM + tid * 4) = o;
}

// ---------------------------------------------------------------------------
extern "C" void kernel_launch(void* const* d_in, const int* in_sizes, int n_in,
                              void* d_out, int out_size, void* d_ws, size_t ws_size,
                              hipStream_t stream)
{
    const float* ent_feat = (const float*)d_in[0];
    const float* rel_feat = (const float*)d_in[1];
    const float* W_head   = (const float*)d_in[2];
    const float* W_tail   = (const float*)d_in[3];
    const float* W_ent    = (const float*)d_in[4];
    const float* W_rel    = (const float*)d_in[5];
    const float* attn     = (const float*)d_in[6];
    const float* ln_ent_g = (const float*)d_in[7];
    const float* ln_ent_b = (const float*)d_in[8];
    const float* ln_rel_g = (const float*)d_in[9];
    const float* ln_rel_b = (const float*)d_in[10];
    const float* ln_ff_g  = (const float*)d_in[11];
    const float* ln_ff_b  = (const float*)d_in[12];
    const float* W1       = (const float*)d_in[13];
    const float* b1       = (const float*)d_in[14];
    const float* W2       = (const float*)d_in[15];
    const float* b2       = (const float*)d_in[16];
    const int*   src      = (const int*)d_in[17];
    const int*   dst      = (const int*)d_in[18];
    const int*   rid      = (const int*)d_in[19];
    float* out = (float*)d_out;

    float* w = (float*)d_ws;
    float* x    = w;               // [N,F] LN(ent); reused later as y
    float* fh   = w + (size_t)NF;      // reused later as t1 (spans fh..bufA = 4*NF)
    float* ftl  = w + 2 * (size_t)NF;
    float* fen  = w + 3 * (size_t)NF;  // feat0
    float* bufA = w + 4 * (size_t)NF;
    float* bufB = w + 5 * (size_t)NF;
    float* rst  = w + 6 * (size_t)NF;
    float* small = w + 7 * (size_t)NF;
    float* r_ln    = small;                         // 25600
    float* fr_rel  = small + 25600;                 // 25600
    float* exa     = small + 51200;                 // E*8 = 2,560,000
    float* denom   = small + 51200 + 2560000;       // 160,000
    int*   deg     = (int*)(denom + 160000);        // 20,000
    float* logdeg  = (float*)(deg + N_NODES);       // 20,000
    int*   offsets = (int*)(logdeg + N_NODES);      // 20,001
    int*   cursor  = offsets + N_NODES + 1;         // 20,000
    int*   eorder  = cursor + N_NODES;              // 320,000
    float* y  = x;
    float* t1 = fh;   // [N, 1024] = 4*NF floats, overlaps fh/ftl/fen/bufA (all dead by then)

    // zero deg (int) + denom (float) — contiguous region
    hipMemsetAsync(denom, 0, (160000 + N_NODES) * sizeof(float), stream);

    // LN
    ln_kernel<<<N_NODES, 64, 0, stream>>>(ent_feat, ln_ent_g, ln_ent_b, x, N_NODES);
    ln_kernel<<<N_REL, 64, 0, stream>>>(rel_feat, ln_rel_g, ln_rel_b, r_ln, N_REL);

    // projections
    dim3 g256((N_NODES + 63) / 64, FDIM / 64);
    gemm_kernel<<<g256, 256, 0, stream>>>(x, W_head, nullptr, nullptr, fh,  N_NODES, FDIM, FDIM, 0);
    gemm_kernel<<<g256, 256, 0, stream>>>(x, W_tail, nullptr, nullptr, ftl, N_NODES, FDIM, FDIM, 0);
    gemm_kernel<<<g256, 256, 0, stream>>>(x, W_ent,  nullptr, nullptr, fen, N_NODES, FDIM, FDIM, 0);
    dim3 grel((N_REL + 63) / 64, FDIM / 64);
    gemm_kernel<<<grel, 256, 0, stream>>>(r_ln, W_rel, nullptr, nullptr, fr_rel, N_REL, FDIM, FDIM, 0);

    // CSR build + degrees
    count_kernel<<<(N_EDGES + 255) / 256, 256, 0, stream>>>(dst, deg, N_EDGES);
    scan_kernel<<<1, 256, 0, stream>>>(deg, offsets, cursor, logdeg, N_NODES);
    scatter_kernel<<<(N_EDGES + 255) / 256, 256, 0, stream>>>(dst, cursor, eorder, N_EDGES);

    // attention scores + softmax
    edge_score_kernel<<<(N_EDGES + 3) / 4, 256, 0, stream>>>(
        fh, ftl, fr_rel, attn, src, dst, rid, logdeg, exa, denom, N_EDGES);
    norm_kernel<<<(N_EDGES * NHEAD + 255) / 256, 256, 0, stream>>>(exa, denom, dst, N_EDGES * NHEAD);

    // 5-hop PPR diffusion (ping-pong): fen -> A -> B -> A -> B -> A
    diffuse_kernel<<<N_NODES, 64, 0, stream>>>(fen,  fen, exa, offsets, eorder, src, bufA);
    diffuse_kernel<<<N_NODES, 64, 0, stream>>>(bufA, fen, exa, offsets, eorder, src, bufB);
    diffuse_kernel<<<N_NODES, 64, 0, stream>>>(bufB, fen, exa, offsets, eorder, src, bufA);
    diffuse_kernel<<<N_NODES, 64, 0, stream>>>(bufA, fen, exa, offsets, eorder, src, bufB);
    diffuse_kernel<<<N_NODES, 64, 0, stream>>>(bufB, fen, exa, offsets, eorder, src, bufA);

    // residual + pre-LN
    rst_ln_kernel<<<N_NODES, 64, 0, stream>>>(bufA, ent_feat, ln_ff_g, ln_ff_b, rst, y);

    // FFN: t1 = relu(y@W1 + b1); out = t1@W2 + b2 + rst
    dim3 gff1((N_NODES + 63) / 64, 1024 / 64);
    gemm_kernel<<<gff1, 256, 0, stream>>>(y, W1, b1, nullptr, t1, N_NODES, FDIM, 1024, 1);
    dim3 gff2((N_NODES + 63) / 64, FDIM / 64);
    gemm_kernel<<<gff2, 256, 0, stream>>>(t1, W2, b2, rst, out, N_NODES, 1024, FDIM, 0);
}

// Round 2
// 793.810 us; speedup vs baseline: 1.3141x; 1.3141x over previous
//
#include <hip/hip_runtime.h>

#define N_NODES 20000
#define N_EDGES 320000
#define N_REL   100
#define FDIM    256
#define NHEAD   8
#define HDIM    32
#define NF      (N_NODES * FDIM)   // 5,120,000 (f32 elements)

using short8 = __attribute__((ext_vector_type(8))) short;   // 8 bf16 in 4 VGPRs
using f32x4  = __attribute__((ext_vector_type(4))) float;

__device__ inline unsigned short f2bf(float f) {
    union { float f; unsigned int u; } v; v.f = f;
    unsigned int r = v.u + 0x7fff + ((v.u >> 16) & 1);   // RNE
    return (unsigned short)(r >> 16);
}

// ---------------------------------------------------------------------------
// LayerNorm over 256 features -> bf16 output. One wave per row.
// ---------------------------------------------------------------------------
__global__ __launch_bounds__(64) void ln_bf16_kernel(
    const float* __restrict__ in, const float* __restrict__ g,
    const float* __restrict__ b, unsigned short* __restrict__ out, int rows)
{
    int row = blockIdx.x;
    if (row >= rows) return;
    int tid = threadIdx.x;
    const float4 v = *(const float4*)(in + (size_t)row * FDIM + tid * 4);
    float s = v.x + v.y + v.z + v.w;
    float q = v.x * v.x + v.y * v.y + v.z * v.z + v.w * v.w;
    #pragma unroll
    for (int d = 1; d < 64; d <<= 1) { s += __shfl_xor(s, d); q += __shfl_xor(q, d); }
    float mean = s * (1.0f / FDIM);
    float var  = q * (1.0f / FDIM) - mean * mean;
    float inv  = rsqrtf(var + 1e-5f);
    float4 gg = *(const float4*)(g + tid * 4);
    float4 bb = *(const float4*)(b + tid * 4);
    ushort4 o;
    o.x = f2bf((v.x - mean) * inv * gg.x + bb.x);
    o.y = f2bf((v.y - mean) * inv * gg.y + bb.y);
    o.z = f2bf((v.z - mean) * inv * gg.z + bb.z);
    o.w = f2bf((v.w - mean) * inv * gg.w + bb.w);
    *(ushort4*)(out + (size_t)row * FDIM + tid * 4) = o;
}

// rst = feat + ent (fp32) ; y = LN(rst) (bf16)
__global__ __launch_bounds__(64) void rst_ln_kernel(
    const float* __restrict__ feat, const float* __restrict__ ent,
    const float* __restrict__ g, const float* __restrict__ b,
    float* __restrict__ rst, unsigned short* __restrict__ y)
{
    int row = blockIdx.x;
    int tid = threadIdx.x;
    const float4 f = *(const float4*)(feat + (size_t)row * FDIM + tid * 4);
    const float4 e = *(const float4*)(ent  + (size_t)row * FDIM + tid * 4);
    float4 r;
    r.x = f.x + e.x; r.y = f.y + e.y; r.z = f.z + e.z; r.w = f.w + e.w;
    *(float4*)(rst + (size_t)row * FDIM + tid * 4) = r;
    float s = r.x + r.y + r.z + r.w;
    float q = r.x * r.x + r.y * r.y + r.z * r.z + r.w * r.w;
    #pragma unroll
    for (int d = 1; d < 64; d <<= 1) { s += __shfl_xor(s, d); q += __shfl_xor(q, d); }
    float mean = s * (1.0f / FDIM);
    float var  = q * (1.0f / FDIM) - mean * mean;
    float inv  = rsqrtf(var + 1e-5f);
    float4 gg = *(const float4*)(g + tid * 4);
    float4 bb = *(const float4*)(b + tid * 4);
    ushort4 o;
    o.x = f2bf((r.x - mean) * inv * gg.x + bb.x);
    o.y = f2bf((r.y - mean) * inv * gg.y + bb.y);
    o.z = f2bf((r.z - mean) * inv * gg.z + bb.z);
    o.w = f2bf((r.w - mean) * inv * gg.w + bb.w);
    *(ushort4*)(y + (size_t)row * FDIM + tid * 4) = o;
}

// Wt[n*K + k] = bf16(W[k*N + n])
__global__ void transpose_bf16_kernel(const float* __restrict__ W,
                                      unsigned short* __restrict__ Wt, int K, int N)
{
    int idx = blockIdx.x * 256 + threadIdx.x;
    if (idx >= K * N) return;
    int n = idx / K, k = idx - n * K;
    Wt[idx] = f2bf(W[(size_t)k * N + n]);
}

// ---------------------------------------------------------------------------
// bf16 MFMA GEMM (B^T form): C[M,N] = A[M,K] @ Bt[N,K]^T  (+bias)(relu)(+add)
// 128x128 tile, 256 threads = 4 waves, 4x4 16x16x32 frags/wave, BK=32.
// A-frag:  A[m = lane&15][k = quad*8 + j]   (verified layout, m89/m120)
// C/D:     col = lane&15, row = quad*4 + reg (verified, m89/m91)
// Output to Cf (fp32) or Cb (bf16), exactly one non-null.
// ---------------------------------------------------------------------------
__global__ __launch_bounds__(256) void mfma_gemm_bt(
    const unsigned short* __restrict__ A, const unsigned short* __restrict__ Bt,
    const float* __restrict__ bias, const float* __restrict__ add,
    float* __restrict__ Cf, unsigned short* __restrict__ Cb,
    int M, int K, int N, int relu)
{
    __shared__ unsigned short As[128 * 32];
    __shared__ unsigned short Bs[128 * 32];
    int tid  = threadIdx.x;
    int wave = tid >> 6, lane = tid & 63;
    int quad = lane >> 4, l16 = lane & 15;
    int m0 = blockIdx.x * 128, n0 = blockIdx.y * 128;
    int wr = (wave >> 1) * 64, wc = (wave & 1) * 64;

    f32x4 acc[4][4] = {};

    // staging coords: chunk c covers row c>>2, k-chunk (c&3)*8 (16B each)
    int cA = tid, cB = tid + 256;
    int rA0 = cA >> 2, kA0 = (cA & 3) * 8;
    int rB0 = cB >> 2, kB0 = (cB & 3) * 8;

    for (int k0 = 0; k0 < K; k0 += 32) {
        {
            int r = m0 + rA0; r = (r < M) ? r : (M - 1);
            ((uint4*)As)[cA] = *(const uint4*)(A + (size_t)r * K + k0 + kA0);
            r = m0 + rB0; r = (r < M) ? r : (M - 1);
            ((uint4*)As)[cB] = *(const uint4*)(A + (size_t)r * K + k0 + kB0);
            ((uint4*)Bs)[cA] = *(const uint4*)(Bt + (size_t)(n0 + rA0) * K + k0 + kA0);
            ((uint4*)Bs)[cB] = *(const uint4*)(Bt + (size_t)(n0 + rB0) * K + k0 + kB0);
        }
        __syncthreads();
        short8 af[4], bfr[4];
        #pragma unroll
        for (int i = 0; i < 4; ++i)
            af[i] = *(const short8*)(As + (wr + i * 16 + l16) * 32 + quad * 8);
        #pragma unroll
        for (int j = 0; j < 4; ++j)
            bfr[j] = *(const short8*)(Bs + (wc + j * 16 + l16) * 32 + quad * 8);
        #pragma unroll
        for (int i = 0; i < 4; ++i)
            #pragma unroll
            for (int j = 0; j < 4; ++j)
                acc[i][j] = __builtin_amdgcn_mfma_f32_16x16x32_bf16(
                    af[i], bfr[j], acc[i][j], 0, 0, 0);
        __syncthreads();
    }

    #pragma unroll
    for (int i = 0; i < 4; ++i) {
        #pragma unroll
        for (int j = 0; j < 4; ++j) {
            int col = n0 + wc + j * 16 + l16;
            float bsv = bias ? bias[col] : 0.0f;
            #pragma unroll
            for (int r = 0; r < 4; ++r) {
                int row = m0 + wr + i * 16 + quad * 4 + r;
                if (row < M) {
                    float v = acc[i][j][r] + bsv;
                    if (relu) v = fmaxf(v, 0.0f);
                    if (add)  v += add[(size_t)row * N + col];
                    if (Cf) Cf[(size_t)row * N + col] = v;
                    else    Cb[(size_t)row * N + col] = f2bf(v);
                }
            }
        }
    }
}

// ---------------------------------------------------------------------------
// Graph plumbing: degree count -> scan (offsets/cursor/logdeg) -> scatter CSR
// ---------------------------------------------------------------------------
__global__ void count_kernel(const int* __restrict__ dst, int* __restrict__ deg, int E)
{
    int i = blockIdx.x * blockDim.x + threadIdx.x;
    if (i < E) atomicAdd(&deg[dst[i]], 1);
}

__global__ __launch_bounds__(256) void scan_kernel(
    const int* __restrict__ deg, int* __restrict__ offsets, int* __restrict__ cursor,
    float* __restrict__ logdeg, int n)
{
    __shared__ int part[256];
    int tid = threadIdx.x;
    int chunk = (n + 255) / 256;
    int lo = tid * chunk;
    int hi = min(lo + chunk, n);
    int s = 0;
    for (int i = lo; i < hi; ++i) s += deg[i];
    part[tid] = s;
    __syncthreads();
    for (int d = 1; d < 256; d <<= 1) {
        int v = part[tid];
        int u = (tid >= d) ? part[tid - d] : 0;
        __syncthreads();
        part[tid] = v + u;
        __syncthreads();
    }
    int run = (tid == 0) ? 0 : part[tid - 1];
    for (int i = lo; i < hi; ++i) {
        offsets[i] = run;
        cursor[i]  = run;
        logdeg[i] = logf((float)deg[i]);
        run += deg[i];
    }
    if (tid == 255) offsets[n] = run;
}

__global__ void scatter_kernel(const int* __restrict__ dst, int* __restrict__ cursor,
                               int* __restrict__ eorder, int E)
{
    int i = blockIdx.x * blockDim.x + threadIdx.x;
    if (i < E) {
        int p = atomicAdd(&cursor[dst[i]], 1);
        eorder[p] = i;
    }
}

// ---------------------------------------------------------------------------
// Edge attention score (fp32). 4 edges per block, 1 wave per edge.
// ---------------------------------------------------------------------------
__global__ __launch_bounds__(256) void edge_score_kernel(
    const float* __restrict__ fh, const float* __restrict__ ftl,
    const float* __restrict__ frel, const float* __restrict__ attn,
    const int* __restrict__ src, const int* __restrict__ dst,
    const int* __restrict__ rid, const float* __restrict__ logdeg,
    float* __restrict__ exbuf, float* __restrict__ denom, int E)
{
    int e = blockIdx.x * 4 + (threadIdx.x >> 6);
    if (e >= E) return;
    int tid = threadIdx.x & 63;
    int s = src[e], t = dst[e], r = rid[e];
    const float4 a4 = *(const float4*)(attn + tid * 4);
    const float4 hv = *(const float4*)(fh  + (size_t)s * FDIM + tid * 4);
    const float4 tv = *(const float4*)(ftl + (size_t)t * FDIM + tid * 4);
    const float4 rv = *(const float4*)(frel + (size_t)r * FDIM + tid * 4);
    float sum = 0.f, p;
    p = hv.x * tv.x * rv.x; p = (p > 0.f) ? p : 0.2f * p; sum += p * a4.x;
    p = hv.y * tv.y * rv.y; p = (p > 0.f) ? p : 0.2f * p; sum += p * a4.y;
    p = hv.z * tv.z * rv.z; p = (p > 0.f) ? p : 0.2f * p; sum += p * a4.z;
    p = hv.w * tv.w * rv.w; p = (p > 0.f) ? p : 0.2f * p; sum += p * a4.w;
    sum += __shfl_xor(sum, 1);
    sum += __shfl_xor(sum, 2);
    sum += __shfl_xor(sum, 4);
    if ((tid & 7) == 0) {
        int h = tid >> 3;
        float escore = sum * logdeg[t] * (1.0f / 32.0f);
        float ex = expf(escore);
        exbuf[(size_t)e * NHEAD + h] = ex;
        atomicAdd(&denom[(size_t)t * NHEAD + h], ex);
    }
}

__global__ void norm_kernel(float* __restrict__ a, const float* __restrict__ denom,
                            const int* __restrict__ dst, int E8)
{
    int i = blockIdx.x * blockDim.x + threadIdx.x;
    if (i < E8) {
        int e = i >> 3;
        a[i] = a[i] / denom[(size_t)dst[e] * NHEAD + (i & 7)];
    }
}

// ---------------------------------------------------------------------------
// One PPR hop, gather form: fout[n] = 0.9*sum_in a*fin[src] + 0.1*feat0[n]
// ---------------------------------------------------------------------------
__global__ __launch_bounds__(64) void diffuse_kernel(
    const float* __restrict__ fin, const float* __restrict__ feat0,
    const float* __restrict__ a, const int* __restrict__ offsets,
    const int* __restrict__ eorder, const int* __restrict__ src,
    float* __restrict__ fout)
{
    int node = blockIdx.x;
    int tid = threadIdx.x;
    int h = tid >> 3;
    int start = offsets[node], end = offsets[node + 1];
    float4 acc = make_float4(0.f, 0.f, 0.f, 0.f);
    for (int pcur = start; pcur < end; ++pcur) {
        int e = eorder[pcur];
        int s = src[e];
        float w = a[(size_t)e * NHEAD + h];
        const float4 f = *(const float4*)(fin + (size_t)s * FDIM + tid * 4);
        acc.x += w * f.x; acc.y += w * f.y; acc.z += w * f.z; acc.w += w * f.w;
    }
    const float4 f0 = *(const float4*)(feat0 + (size_t)node * FDIM + tid * 4);
    float4 o;
    o.x = 0.9f * acc.x + 0.1f * f0.x;
    o.y = 0.9f * acc.y + 0.1f * f0.y;
    o.z = 0.9f * acc.z + 0.1f * f0.z;
    o.w = 0.9f * acc.w + 0.1f * f0.w;
    *(float4*)(fout + (size_t)node * FDIM + tid * 4) = o;
}

// ---------------------------------------------------------------------------
extern "C" void kernel_launch(void* const* d_in, const int* in_sizes, int n_in,
                              void* d_out, int out_size, void* d_ws, size_t ws_size,
                              hipStream_t stream)
{
    const float* ent_feat = (const float*)d_in[0];
    const float* rel_feat = (const float*)d_in[1];
    const float* W_head   = (const float*)d_in[2];
    const float* W_tail   = (const float*)d_in[3];
    const float* W_ent    = (const float*)d_in[4];
    const float* W_rel    = (const float*)d_in[5];
    const float* attn     = (const float*)d_in[6];
    const float* ln_ent_g = (const float*)d_in[7];
    const float* ln_ent_b = (const float*)d_in[8];
    const float* ln_rel_g = (const float*)d_in[9];
    const float* ln_rel_b = (const float*)d_in[10];
    const float* ln_ff_g  = (const float*)d_in[11];
    const float* ln_ff_b  = (const float*)d_in[12];
    const float* W1       = (const float*)d_in[13];
    const float* b1       = (const float*)d_in[14];
    const float* W2       = (const float*)d_in[15];
    const float* b2       = (const float*)d_in[16];
    const int*   src      = (const int*)d_in[17];
    const int*   dst      = (const int*)d_in[18];
    const int*   rid      = (const int*)d_in[19];
    float* out = (float*)d_out;

    float* w = (float*)d_ws;
    // main slots (f32 units)
    unsigned short* xb = (unsigned short*)w;                 // [N,F] bf16 (slot 0 first half)
    unsigned short* yb = ((unsigned short*)w) + NF;          // [N,F] bf16 (slot 0 second half)
    float* fh   = w + 1 * (size_t)NF;
    float* ftl  = w + 2 * (size_t)NF;
    float* fen  = w + 3 * (size_t)NF;    // feat0
    float* bufA = w + 4 * (size_t)NF;
    float* bufB = w + 5 * (size_t)NF;
    float* rst  = w + 6 * (size_t)NF;
    float* small = w + 7 * (size_t)NF;
    // t1 bf16 [N,1024] aliases fh..ftl (dead by FFN time)
    unsigned short* t1b = (unsigned short*)fh;
    // projection/rel weight transposes + r_ln alias bufA (dead before hop 1)
    unsigned short* WtH  = (unsigned short*)bufA;            // 65536 each
    unsigned short* WtT  = WtH + 65536;
    unsigned short* WtE  = WtT + 65536;
    unsigned short* WtR  = WtE + 65536;
    unsigned short* rlnb = WtR + 65536;                      // 25600
    // FFN weight transposes alias bufB (dead after hop 5; transposed just before FFN)
    unsigned short* W1t = (unsigned short*)bufB;             // 262144
    unsigned short* W2t = W1t + 262144;                      // 262144
    // small region
    float* fr_rel  = small;                         // 25600
    float* exa     = small + 25600;                 // 2,560,000
    float* denom   = small + 25600 + 2560000;       // 160,000
    int*   deg     = (int*)(denom + 160000);        // 20,000
    float* logdeg  = (float*)(deg + N_NODES);       // 20,000
    int*   offsets = (int*)(logdeg + N_NODES);      // 20,001
    int*   cursor  = offsets + N_NODES + 1;         // 20,000
    int*   eorder  = cursor + N_NODES;              // 320,000
    float* yout = out;

    hipMemsetAsync(denom, 0, (160000 + N_NODES) * sizeof(float), stream);

    // LN (bf16 outputs for GEMM A operands)
    ln_bf16_kernel<<<N_NODES, 64, 0, stream>>>(ent_feat, ln_ent_g, ln_ent_b, xb, N_NODES);
    ln_bf16_kernel<<<N_REL, 64, 0, stream>>>(rel_feat, ln_rel_g, ln_rel_b, rlnb, N_REL);

    // weight transposes (fp32 [K,N] -> bf16 [N,K])
    transpose_bf16_kernel<<<(65536 + 255) / 256, 256, 0, stream>>>(W_head, WtH, FDIM, FDIM);
    transpose_bf16_kernel<<<(65536 + 255) / 256, 256, 0, stream>>>(W_tail, WtT, FDIM, FDIM);
    transpose_bf16_kernel<<<(65536 + 255) / 256, 256, 0, stream>>>(W_ent,  WtE, FDIM, FDIM);
    transpose_bf16_kernel<<<(65536 + 255) / 256, 256, 0, stream>>>(W_rel,  WtR, FDIM, FDIM);

    // projections (MFMA bf16, fp32 out)
    dim3 gproj((N_NODES + 127) / 128, FDIM / 128);
    mfma_gemm_bt<<<gproj, 256, 0, stream>>>(xb, WtH, nullptr, nullptr, fh,  nullptr, N_NODES, FDIM, FDIM, 0);
    mfma_gemm_bt<<<gproj, 256, 0, stream>>>(xb, WtT, nullptr, nullptr, ftl, nullptr, N_NODES, FDIM, FDIM, 0);
    mfma_gemm_bt<<<gproj, 256, 0, stream>>>(xb, WtE, nullptr, nullptr, fen, nullptr, N_NODES, FDIM, FDIM, 0);
    dim3 grel(1, FDIM / 128);
    mfma_gemm_bt<<<grel, 256, 0, stream>>>(rlnb, WtR, nullptr, nullptr, fr_rel, nullptr, N_REL, FDIM, FDIM, 0);

    // CSR build + degrees
    count_kernel<<<(N_EDGES + 255) / 256, 256, 0, stream>>>(dst, deg, N_EDGES);
    scan_kernel<<<1, 256, 0, stream>>>(deg, offsets, cursor, logdeg, N_NODES);
    scatter_kernel<<<(N_EDGES + 255) / 256, 256, 0, stream>>>(dst, cursor, eorder, N_EDGES);

    // attention scores + softmax
    edge_score_kernel<<<(N_EDGES + 3) / 4, 256, 0, stream>>>(
        fh, ftl, fr_rel, attn, src, dst, rid, logdeg, exa, denom, N_EDGES);
    norm_kernel<<<(N_EDGES * NHEAD + 255) / 256, 256, 0, stream>>>(exa, denom, dst, N_EDGES * NHEAD);

    // 5-hop PPR diffusion: fen -> A -> B -> A -> B -> A
    diffuse_kernel<<<N_NODES, 64, 0, stream>>>(fen,  fen, exa, offsets, eorder, src, bufA);
    diffuse_kernel<<<N_NODES, 64, 0, stream>>>(bufA, fen, exa, offsets, eorder, src, bufB);
    diffuse_kernel<<<N_NODES, 64, 0, stream>>>(bufB, fen, exa, offsets, eorder, src, bufA);
    diffuse_kernel<<<N_NODES, 64, 0, stream>>>(bufA, fen, exa, offsets, eorder, src, bufB);
    diffuse_kernel<<<N_NODES, 64, 0, stream>>>(bufB, fen, exa, offsets, eorder, src, bufA);

    // residual + pre-LN (rst fp32, y bf16)
    rst_ln_kernel<<<N_NODES, 64, 0, stream>>>(bufA, ent_feat, ln_ff_g, ln_ff_b, rst, yb);

    // FFN weight transposes into bufB (now dead)
    transpose_bf16_kernel<<<(262144 + 255) / 256, 256, 0, stream>>>(W1, W1t, FDIM, 1024);
    transpose_bf16_kernel<<<(262144 + 255) / 256, 256, 0, stream>>>(W2, W2t, 1024, FDIM);

    // FFN: t1 = relu(y@W1 + b1) [bf16]; out = t1@W2 + b2 + rst [fp32]
    dim3 gff1((N_NODES + 127) / 128, 1024 / 128);
    mfma_gemm_bt<<<gff1, 256, 0, stream>>>(yb, W1t, b1, nullptr, nullptr, t1b, N_NODES, FDIM, 1024, 1);
    dim3 gff2((N_NODES + 127) / 128, FDIM / 128);
    mfma_gemm_bt<<<gff2, 256, 0, stream>>>(t1b, W2t, b2, rst, yout, nullptr, N_NODES, 1024, FDIM, 0);
}

// Round 3
// 590.982 us; speedup vs baseline: 1.7652x; 1.3432x over previous
//
#include <hip/hip_runtime.h>

#define N_NODES 20000
#define N_EDGES 320000
#define N_REL   100
#define FDIM    256
#define NHEAD   8
#define HDIM    32

using short8 = __attribute__((ext_vector_type(8))) short;   // 8 bf16 in 4 VGPRs
using f32x4  = __attribute__((ext_vector_type(4))) float;

__device__ inline unsigned short f2bf(float f) {
    union { float f; unsigned int u; } v; v.f = f;
    unsigned int r = v.u + 0x7fff + ((v.u >> 16) & 1);   // RNE
    return (unsigned short)(r >> 16);
}
__device__ inline float bf2f(unsigned short u) {
    union { unsigned int i; float f; } v; v.i = ((unsigned int)u) << 16; return v.f;
}
__device__ inline float4 bf4(ushort4 u) {
    return make_float4(bf2f(u.x), bf2f(u.y), bf2f(u.z), bf2f(u.w));
}

// ---------------------------------------------------------------------------
// LayerNorm over 256 features -> bf16 output. One wave per row.
// ---------------------------------------------------------------------------
__global__ __launch_bounds__(64) void ln_bf16_kernel(
    const float* __restrict__ in, const float* __restrict__ g,
    const float* __restrict__ b, unsigned short* __restrict__ out, int rows)
{
    int row = blockIdx.x;
    if (row >= rows) return;
    int tid = threadIdx.x;
    const float4 v = *(const float4*)(in + (size_t)row * FDIM + tid * 4);
    float s = v.x + v.y + v.z + v.w;
    float q = v.x * v.x + v.y * v.y + v.z * v.z + v.w * v.w;
    #pragma unroll
    for (int d = 1; d < 64; d <<= 1) { s += __shfl_xor(s, d); q += __shfl_xor(q, d); }
    float mean = s * (1.0f / FDIM);
    float var  = q * (1.0f / FDIM) - mean * mean;
    float inv  = rsqrtf(var + 1e-5f);
    float4 gg = *(const float4*)(g + tid * 4);
    float4 bb = *(const float4*)(b + tid * 4);
    ushort4 o;
    o.x = f2bf((v.x - mean) * inv * gg.x + bb.x);
    o.y = f2bf((v.y - mean) * inv * gg.y + bb.y);
    o.z = f2bf((v.z - mean) * inv * gg.z + bb.z);
    o.w = f2bf((v.w - mean) * inv * gg.w + bb.w);
    *(ushort4*)(out + (size_t)row * FDIM + tid * 4) = o;
}

// rst = bf2f(feat) + ent (fp32) ; y = LN(rst) (bf16)
__global__ __launch_bounds__(64) void rst_ln_kernel(
    const unsigned short* __restrict__ feat, const float* __restrict__ ent,
    const float* __restrict__ g, const float* __restrict__ b,
    float* __restrict__ rst, unsigned short* __restrict__ y)
{
    int row = blockIdx.x;
    int tid = threadIdx.x;
    const float4 f = bf4(*(const ushort4*)(feat + (size_t)row * FDIM + tid * 4));
    const float4 e = *(const float4*)(ent + (size_t)row * FDIM + tid * 4);
    float4 r;
    r.x = f.x + e.x; r.y = f.y + e.y; r.z = f.z + e.z; r.w = f.w + e.w;
    *(float4*)(rst + (size_t)row * FDIM + tid * 4) = r;
    float s = r.x + r.y + r.z + r.w;
    float q = r.x * r.x + r.y * r.y + r.z * r.z + r.w * r.w;
    #pragma unroll
    for (int d = 1; d < 64; d <<= 1) { s += __shfl_xor(s, d); q += __shfl_xor(q, d); }
    float mean = s * (1.0f / FDIM);
    float var  = q * (1.0f / FDIM) - mean * mean;
    float inv  = rsqrtf(var + 1e-5f);
    float4 gg = *(const float4*)(g + tid * 4);
    float4 bb = *(const float4*)(b + tid * 4);
    ushort4 o;
    o.x = f2bf((r.x - mean) * inv * gg.x + bb.x);
    o.y = f2bf((r.y - mean) * inv * gg.y + bb.y);
    o.z = f2bf((r.z - mean) * inv * gg.z + bb.z);
    o.w = f2bf((r.w - mean) * inv * gg.w + bb.w);
    *(ushort4*)(y + (size_t)row * FDIM + tid * 4) = o;
}

// Wt[n*K + k] = bf16(W[k*N + n])
__global__ void transpose_bf16_kernel(const float* __restrict__ W,
                                      unsigned short* __restrict__ Wt, int K, int N)
{
    int idx = blockIdx.x * 256 + threadIdx.x;
    if (idx >= K * N) return;
    int n = idx / K, k = idx - n * K;
    Wt[idx] = f2bf(W[(size_t)k * N + n]);
}

// ---------------------------------------------------------------------------
// bf16 MFMA GEMM (B^T): C[M,N] = A[M,K] @ Bt[N,K]^T  (+bias)(relu)(+add)
// 128x128 tile, 4 waves, 4x4 16x16x32 frags/wave, BK=32. Verified layouts.
// ---------------------------------------------------------------------------
__global__ __launch_bounds__(256) void mfma_gemm_bt(
    const unsigned short* __restrict__ A, const unsigned short* __restrict__ Bt,
    const float* __restrict__ bias, const float* __restrict__ add,
    float* __restrict__ Cf, unsigned short* __restrict__ Cb,
    int M, int K, int N, int relu)
{
    __shared__ unsigned short As[128 * 32];
    __shared__ unsigned short Bs[128 * 32];
    int tid  = threadIdx.x;
    int wave = tid >> 6, lane = tid & 63;
    int quad = lane >> 4, l16 = lane & 15;
    int m0 = blockIdx.x * 128, n0 = blockIdx.y * 128;
    int wr = (wave >> 1) * 64, wc = (wave & 1) * 64;

    f32x4 acc[4][4] = {};

    int cA = tid, cB = tid + 256;
    int rA0 = cA >> 2, kA0 = (cA & 3) * 8;
    int rB0 = cB >> 2, kB0 = (cB & 3) * 8;

    for (int k0 = 0; k0 < K; k0 += 32) {
        {
            int r = m0 + rA0; r = (r < M) ? r : (M - 1);
            ((uint4*)As)[cA] = *(const uint4*)(A + (size_t)r * K + k0 + kA0);
            r = m0 + rB0; r = (r < M) ? r : (M - 1);
            ((uint4*)As)[cB] = *(const uint4*)(A + (size_t)r * K + k0 + kB0);
            ((uint4*)Bs)[cA] = *(const uint4*)(Bt + (size_t)(n0 + rA0) * K + k0 + kA0);
            ((uint4*)Bs)[cB] = *(const uint4*)(Bt + (size_t)(n0 + rB0) * K + k0 + kB0);
        }
        __syncthreads();
        short8 af[4], bfr[4];
        #pragma unroll
        for (int i = 0; i < 4; ++i)
            af[i] = *(const short8*)(As + (wr + i * 16 + l16) * 32 + quad * 8);
        #pragma unroll
        for (int j = 0; j < 4; ++j)
            bfr[j] = *(const short8*)(Bs + (wc + j * 16 + l16) * 32 + quad * 8);
        #pragma unroll
        for (int i = 0; i < 4; ++i)
            #pragma unroll
            for (int j = 0; j < 4; ++j)
                acc[i][j] = __builtin_amdgcn_mfma_f32_16x16x32_bf16(
                    af[i], bfr[j], acc[i][j], 0, 0, 0);
        __syncthreads();
    }

    #pragma unroll
    for (int i = 0; i < 4; ++i) {
        #pragma unroll
        for (int j = 0; j < 4; ++j) {
            int col = n0 + wc + j * 16 + l16;
            float bsv = bias ? bias[col] : 0.0f;
            #pragma unroll
            for (int r = 0; r < 4; ++r) {
                int row = m0 + wr + i * 16 + quad * 4 + r;
                if (row < M) {
                    float v = acc[i][j][r] + bsv;
                    if (relu) v = fmaxf(v, 0.0f);
                    if (add)  v += add[(size_t)row * N + col];
                    if (Cf) Cf[(size_t)row * N + col] = v;
                    else    Cb[(size_t)row * N + col] = f2bf(v);
                }
            }
        }
    }
}

// ---------------------------------------------------------------------------
// Graph plumbing: degree count -> scan -> scatter (builds csr_src/csr_rid)
// ---------------------------------------------------------------------------
__global__ void count_kernel(const int* __restrict__ dst, int* __restrict__ deg, int E)
{
    int i = blockIdx.x * blockDim.x + threadIdx.x;
    if (i < E) atomicAdd(&deg[dst[i]], 1);
}

__global__ __launch_bounds__(256) void scan_kernel(
    const int* __restrict__ deg, int* __restrict__ offsets, int* __restrict__ cursor,
    float* __restrict__ logdeg, int n)
{
    __shared__ int part[256];
    int tid = threadIdx.x;
    int chunk = (n + 255) / 256;
    int lo = tid * chunk;
    int hi = min(lo + chunk, n);
    int s = 0;
    for (int i = lo; i < hi; ++i) s += deg[i];
    part[tid] = s;
    __syncthreads();
    for (int d = 1; d < 256; d <<= 1) {
        int v = part[tid];
        int u = (tid >= d) ? part[tid - d] : 0;
        __syncthreads();
        part[tid] = v + u;
        __syncthreads();
    }
    int run = (tid == 0) ? 0 : part[tid - 1];
    for (int i = lo; i < hi; ++i) {
        offsets[i] = run;
        cursor[i]  = run;
        logdeg[i] = logf((float)deg[i]);
        run += deg[i];
    }
    if (tid == 255) offsets[n] = run;
}

__global__ void scatter_kernel(const int* __restrict__ dst, const int* __restrict__ src,
                               const int* __restrict__ rid, int* __restrict__ cursor,
                               int* __restrict__ csr_src, int* __restrict__ csr_rid, int E)
{
    int i = blockIdx.x * blockDim.x + threadIdx.x;
    if (i < E) {
        int p = atomicAdd(&cursor[dst[i]], 1);
        csr_src[p] = src[i];
        csr_rid[p] = rid[i];
    }
}

// ---------------------------------------------------------------------------
// CSR edge attention + fused softmax. One wave per dst node (4 per block).
// ftl[dst] loaded once per node; denominator in registers; writes normalized
// a[p][8] in CSR order. (Segment-max subtraction skipped: softmax-invariant,
// |score| small -> no fp32 exp overflow.)
// ---------------------------------------------------------------------------
__global__ __launch_bounds__(256) void edge_score_csr_kernel(
    const unsigned short* __restrict__ proj,   // [N,768]: fh | ftl | fen
    const unsigned short* __restrict__ frel,   // [R,256] bf16
    const float* __restrict__ attn,
    const int* __restrict__ csr_src, const int* __restrict__ csr_rid,
    const int* __restrict__ offsets, const float* __restrict__ logdeg,
    float* __restrict__ csr_a, int n)
{
    int node = blockIdx.x * 4 + (threadIdx.x >> 6);
    if (node >= n) return;
    int tid = threadIdx.x & 63;
    int start = offsets[node], end = offsets[node + 1];
    float scale = logdeg[node] * (1.0f / 32.0f);
    float4 tv = bf4(*(const ushort4*)(proj + (size_t)node * 768 + 256 + tid * 4));
    float4 a4 = *(const float4*)(attn + tid * 4);
    bool leader = ((tid & 7) == 0);
    int h = tid >> 3;
    float denom = 0.f;
    for (int p = start; p < end; ++p) {
        int s = csr_src[p];
        int r = csr_rid[p];
        float4 hv = bf4(*(const ushort4*)(proj + (size_t)s * 768 + tid * 4));
        float4 rv = bf4(*(const ushort4*)(frel + (size_t)r * FDIM + tid * 4));
        float sum = 0.f, pp;
        pp = hv.x * tv.x * rv.x; pp = (pp > 0.f) ? pp : 0.2f * pp; sum += pp * a4.x;
        pp = hv.y * tv.y * rv.y; pp = (pp > 0.f) ? pp : 0.2f * pp; sum += pp * a4.y;
        pp = hv.z * tv.z * rv.z; pp = (pp > 0.f) ? pp : 0.2f * pp; sum += pp * a4.z;
        pp = hv.w * tv.w * rv.w; pp = (pp > 0.f) ? pp : 0.2f * pp; sum += pp * a4.w;
        sum += __shfl_xor(sum, 1);
        sum += __shfl_xor(sum, 2);
        sum += __shfl_xor(sum, 4);
        if (leader) {
            float ex = expf(sum * scale);
            csr_a[(size_t)p * NHEAD + h] = ex;
            denom += ex;
        }
    }
    // normalize: denom lives in lanes h*8; broadcast to all lanes
    float dh = __shfl(denom, (tid & 7) << 3);
    for (int i = start * NHEAD + tid; i < end * NHEAD; i += 64)
        csr_a[i] = csr_a[i] / dh;
}

// ---------------------------------------------------------------------------
// One PPR hop (bf16): fout[n] = bf16(0.9*sum_in a*fin[src] + 0.1*feat0[n])
// One wave per node; fin/feat0 have arbitrary row strides (proj aliasing).
// ---------------------------------------------------------------------------
__global__ __launch_bounds__(64) void diffuse_kernel(
    const unsigned short* __restrict__ fin, int fin_stride,
    const unsigned short* __restrict__ feat0,
    const float* __restrict__ a, const int* __restrict__ csr_src,
    const int* __restrict__ offsets, unsigned short* __restrict__ fout)
{
    int node = blockIdx.x;
    int tid = threadIdx.x;
    int h = tid >> 3;
    int start = offsets[node], end = offsets[node + 1];
    float4 acc = make_float4(0.f, 0.f, 0.f, 0.f);
    for (int p = start; p < end; ++p) {
        int s = csr_src[p];
        float w = a[(size_t)p * NHEAD + h];
        float4 f = bf4(*(const ushort4*)(fin + (size_t)s * fin_stride + tid * 4));
        acc.x += w * f.x; acc.y += w * f.y; acc.z += w * f.z; acc.w += w * f.w;
    }
    float4 f0 = bf4(*(const ushort4*)(feat0 + (size_t)node * 768 + tid * 4));
    ushort4 o;
    o.x = f2bf(0.9f * acc.x + 0.1f * f0.x);
    o.y = f2bf(0.9f * acc.y + 0.1f * f0.y);
    o.z = f2bf(0.9f * acc.z + 0.1f * f0.z);
    o.w = f2bf(0.9f * acc.w + 0.1f * f0.w);
    *(ushort4*)(fout + (size_t)node * FDIM + tid * 4) = o;
}

// ---------------------------------------------------------------------------
extern "C" void kernel_launch(void* const* d_in, const int* in_sizes, int n_in,
                              void* d_out, int out_size, void* d_ws, size_t ws_size,
                              hipStream_t stream)
{
    const float* ent_feat = (const float*)d_in[0];
    const float* rel_feat = (const float*)d_in[1];
    const float* W_head   = (const float*)d_in[2];
    const float* W_tail   = (const float*)d_in[3];
    const float* W_ent    = (const float*)d_in[4];
    const float* W_rel    = (const float*)d_in[5];
    const float* attn     = (const float*)d_in[6];
    const float* ln_ent_g = (const float*)d_in[7];
    const float* ln_ent_b = (const float*)d_in[8];
    const float* ln_rel_g = (const float*)d_in[9];
    const float* ln_rel_b = (const float*)d_in[10];
    const float* ln_ff_g  = (const float*)d_in[11];
    const float* ln_ff_b  = (const float*)d_in[12];
    const float* W1       = (const float*)d_in[13];
    const float* b1       = (const float*)d_in[14];
    const float* W2       = (const float*)d_in[15];
    const float* b2       = (const float*)d_in[16];
    const int*   src      = (const int*)d_in[17];
    const int*   dst      = (const int*)d_in[18];
    const int*   rid      = (const int*)d_in[19];
    float* out = (float*)d_out;

    // ---- workspace carve (bytes, 256-aligned) ----
    char* base = (char*)d_ws;
    auto carve = [&](size_t bytes) { char* p = base; base += (bytes + 255) & ~(size_t)255; return p; };
    unsigned short* xb    = (unsigned short*)carve((size_t)N_NODES * FDIM * 2);    // LN(ent) bf16
    unsigned short* projb = (unsigned short*)carve((size_t)N_NODES * 768 * 2);     // fh|ftl|fen bf16
    unsigned short* rlnb  = (unsigned short*)carve((size_t)N_REL * FDIM * 2);
    unsigned short* frelb = (unsigned short*)carve((size_t)N_REL * FDIM * 2);
    unsigned short* WtP   = (unsigned short*)carve((size_t)768 * FDIM * 2);        // head|tail|ent ^T
    unsigned short* WtR   = (unsigned short*)carve((size_t)FDIM * FDIM * 2);
    unsigned short* W1t   = (unsigned short*)carve((size_t)1024 * FDIM * 2);
    unsigned short* W2t   = (unsigned short*)carve((size_t)FDIM * 1024 * 2);
    unsigned short* hb0   = (unsigned short*)carve((size_t)N_NODES * FDIM * 2);
    unsigned short* hb1   = (unsigned short*)carve((size_t)N_NODES * FDIM * 2);
    unsigned short* yb    = (unsigned short*)carve((size_t)N_NODES * FDIM * 2);
    unsigned short* t1b   = (unsigned short*)carve((size_t)N_NODES * 1024 * 2);
    float* rst     = (float*)carve((size_t)N_NODES * FDIM * 4);
    float* csr_a   = (float*)carve((size_t)N_EDGES * NHEAD * 4);
    int*   csr_src = (int*)carve((size_t)N_EDGES * 4);
    int*   csr_rid = (int*)carve((size_t)N_EDGES * 4);
    int*   deg     = (int*)carve((size_t)N_NODES * 4);
    float* logdeg  = (float*)carve((size_t)N_NODES * 4);
    int*   offsets = (int*)carve((size_t)(N_NODES + 1) * 4);
    int*   cursor  = (int*)carve((size_t)N_NODES * 4);

    hipMemsetAsync(deg, 0, (size_t)N_NODES * 4, stream);

    // LN -> bf16
    ln_bf16_kernel<<<N_NODES, 64, 0, stream>>>(ent_feat, ln_ent_g, ln_ent_b, xb, N_NODES);
    ln_bf16_kernel<<<N_REL, 64, 0, stream>>>(rel_feat, ln_rel_g, ln_rel_b, rlnb, N_REL);

    // weight transposes (fp32 [K,N] -> bf16 [N,K]); WtP rows = [head | tail | ent]
    transpose_bf16_kernel<<<(65536 + 255) / 256, 256, 0, stream>>>(W_head, WtP,               FDIM, FDIM);
    transpose_bf16_kernel<<<(65536 + 255) / 256, 256, 0, stream>>>(W_tail, WtP + 256 * FDIM,  FDIM, FDIM);
    transpose_bf16_kernel<<<(65536 + 255) / 256, 256, 0, stream>>>(W_ent,  WtP + 512 * FDIM,  FDIM, FDIM);
    transpose_bf16_kernel<<<(65536 + 255) / 256, 256, 0, stream>>>(W_rel,  WtR, FDIM, FDIM);
    transpose_bf16_kernel<<<(262144 + 255) / 256, 256, 0, stream>>>(W1, W1t, FDIM, 1024);
    transpose_bf16_kernel<<<(262144 + 255) / 256, 256, 0, stream>>>(W2, W2t, 1024, FDIM);

    // fused projection GEMM: proj[N,768] = xb @ [Wh|Wt|We]  (bf16 out)
    dim3 gproj((N_NODES + 127) / 128, 768 / 128);
    mfma_gemm_bt<<<gproj, 256, 0, stream>>>(xb, WtP, nullptr, nullptr, nullptr, projb,
                                            N_NODES, FDIM, 768, 0);
    dim3 grel(1, FDIM / 128);
    mfma_gemm_bt<<<grel, 256, 0, stream>>>(rlnb, WtR, nullptr, nullptr, nullptr, frelb,
                                           N_REL, FDIM, FDIM, 0);

    // CSR build
    count_kernel<<<(N_EDGES + 255) / 256, 256, 0, stream>>>(dst, deg, N_EDGES);
    scan_kernel<<<1, 256, 0, stream>>>(deg, offsets, cursor, logdeg, N_NODES);
    scatter_kernel<<<(N_EDGES + 255) / 256, 256, 0, stream>>>(dst, src, rid, cursor,
                                                              csr_src, csr_rid, N_EDGES);

    // attention + fused softmax (normalized a in CSR order)
    edge_score_csr_kernel<<<(N_NODES + 3) / 4, 256, 0, stream>>>(
        projb, frelb, attn, csr_src, csr_rid, offsets, logdeg, csr_a, N_NODES);

    // 5-hop PPR diffusion (bf16): fen(proj+512) -> hb0 -> hb1 -> hb0 -> hb1 -> hb0
    const unsigned short* fen = projb + 512;
    diffuse_kernel<<<N_NODES, 64, 0, stream>>>(fen, 768, fen, csr_a, csr_src, offsets, hb0);
    diffuse_kernel<<<N_NODES, 64, 0, stream>>>(hb0, FDIM, fen, csr_a, csr_src, offsets, hb1);
    diffuse_kernel<<<N_NODES, 64, 0, stream>>>(hb1, FDIM, fen, csr_a, csr_src, offsets, hb0);
    diffuse_kernel<<<N_NODES, 64, 0, stream>>>(hb0, FDIM, fen, csr_a, csr_src, offsets, hb1);
    diffuse_kernel<<<N_NODES, 64, 0, stream>>>(hb1, FDIM, fen, csr_a, csr_src, offsets, hb0);

    // residual + pre-LN
    rst_ln_kernel<<<N_NODES, 64, 0, stream>>>(hb0, ent_feat, ln_ff_g, ln_ff_b, rst, yb);

    // FFN: t1 = relu(y@W1 + b1) [bf16]; out = t1@W2 + b2 + rst [fp32]
    dim3 gff1((N_NODES + 127) / 128, 1024 / 128);
    mfma_gemm_bt<<<gff1, 256, 0, stream>>>(yb, W1t, b1, nullptr, nullptr, t1b,
                                           N_NODES, FDIM, 1024, 1);
    dim3 gff2((N_NODES + 127) / 128, FDIM / 128);
    mfma_gemm_bt<<<gff2, 256, 0, stream>>>(t1b, W2t, b2, rst, out, nullptr,
                                           N_NODES, 1024, FDIM, 0);
}

// Round 4
// 571.453 us; speedup vs baseline: 1.8255x; 1.0342x over previous
//
#include <hip/hip_runtime.h>

#define N_NODES 20000
#define N_EDGES 320000
#define N_REL   100
#define FDIM    256
#define NHEAD   8
#define HDIM    32

using short8 = __attribute__((ext_vector_type(8))) short;   // 8 bf16 in 4 VGPRs
using f32x4  = __attribute__((ext_vector_type(4))) float;

__device__ inline unsigned short f2bf(float f) {
    union { float f; unsigned int u; } v; v.f = f;
    unsigned int r = v.u + 0x7fff + ((v.u >> 16) & 1);   // RNE
    return (unsigned short)(r >> 16);
}
__device__ inline float bf2f(unsigned short u) {
    union { unsigned int i; float f; } v; v.i = ((unsigned int)u) << 16; return v.f;
}
__device__ inline float4 bf4(ushort4 u) {
    return make_float4(bf2f(u.x), bf2f(u.y), bf2f(u.z), bf2f(u.w));
}

// ---------------------------------------------------------------------------
// LayerNorm over 256 features -> bf16 output. One wave per row.
// ---------------------------------------------------------------------------
__global__ __launch_bounds__(64) void ln_bf16_kernel(
    const float* __restrict__ in, const float* __restrict__ g,
    const float* __restrict__ b, unsigned short* __restrict__ out, int rows)
{
    int row = blockIdx.x;
    if (row >= rows) return;
    int tid = threadIdx.x;
    const float4 v = *(const float4*)(in + (size_t)row * FDIM + tid * 4);
    float s = v.x + v.y + v.z + v.w;
    float q = v.x * v.x + v.y * v.y + v.z * v.z + v.w * v.w;
    #pragma unroll
    for (int d = 1; d < 64; d <<= 1) { s += __shfl_xor(s, d); q += __shfl_xor(q, d); }
    float mean = s * (1.0f / FDIM);
    float var  = q * (1.0f / FDIM) - mean * mean;
    float inv  = rsqrtf(var + 1e-5f);
    float4 gg = *(const float4*)(g + tid * 4);
    float4 bb = *(const float4*)(b + tid * 4);
    ushort4 o;
    o.x = f2bf((v.x - mean) * inv * gg.x + bb.x);
    o.y = f2bf((v.y - mean) * inv * gg.y + bb.y);
    o.z = f2bf((v.z - mean) * inv * gg.z + bb.z);
    o.w = f2bf((v.w - mean) * inv * gg.w + bb.w);
    *(ushort4*)(out + (size_t)row * FDIM + tid * 4) = o;
}

// rst = bf2f(feat) + ent (fp32) ; y = LN(rst) (bf16)
__global__ __launch_bounds__(64) void rst_ln_kernel(
    const unsigned short* __restrict__ feat, const float* __restrict__ ent,
    const float* __restrict__ g, const float* __restrict__ b,
    float* __restrict__ rst, unsigned short* __restrict__ y)
{
    int row = blockIdx.x;
    int tid = threadIdx.x;
    const float4 f = bf4(*(const ushort4*)(feat + (size_t)row * FDIM + tid * 4));
    const float4 e = *(const float4*)(ent + (size_t)row * FDIM + tid * 4);
    float4 r;
    r.x = f.x + e.x; r.y = f.y + e.y; r.z = f.z + e.z; r.w = f.w + e.w;
    *(float4*)(rst + (size_t)row * FDIM + tid * 4) = r;
    float s = r.x + r.y + r.z + r.w;
    float q = r.x * r.x + r.y * r.y + r.z * r.z + r.w * r.w;
    #pragma unroll
    for (int d = 1; d < 64; d <<= 1) { s += __shfl_xor(s, d); q += __shfl_xor(q, d); }
    float mean = s * (1.0f / FDIM);
    float var  = q * (1.0f / FDIM) - mean * mean;
    float inv  = rsqrtf(var + 1e-5f);
    float4 gg = *(const float4*)(g + tid * 4);
    float4 bb = *(const float4*)(b + tid * 4);
    ushort4 o;
    o.x = f2bf((r.x - mean) * inv * gg.x + bb.x);
    o.y = f2bf((r.y - mean) * inv * gg.y + bb.y);
    o.z = f2bf((r.z - mean) * inv * gg.z + bb.z);
    o.w = f2bf((r.w - mean) * inv * gg.w + bb.w);
    *(ushort4*)(y + (size_t)row * FDIM + tid * 4) = o;
}

// Wt[n*K + k] = bf16(W[k*N + n])
__global__ void transpose_bf16_kernel(const float* __restrict__ W,
                                      unsigned short* __restrict__ Wt, int K, int N)
{
    int idx = blockIdx.x * 256 + threadIdx.x;
    if (idx >= K * N) return;
    int n = idx / K, k = idx - n * K;
    Wt[idx] = f2bf(W[(size_t)k * N + n]);
}

// ---------------------------------------------------------------------------
// bf16 MFMA GEMM (B^T): C[M,N] = A[M,K] @ Bt[N,K]^T  (+bias)(relu)(+add)
// 128x128 tile, 4 waves, 4x4 16x16x32 frags/wave, BK=32. Verified layouts.
// ---------------------------------------------------------------------------
__global__ __launch_bounds__(256) void mfma_gemm_bt(
    const unsigned short* __restrict__ A, const unsigned short* __restrict__ Bt,
    const float* __restrict__ bias, const float* __restrict__ add,
    float* __restrict__ Cf, unsigned short* __restrict__ Cb,
    int M, int K, int N, int relu)
{
    __shared__ unsigned short As[128 * 32];
    __shared__ unsigned short Bs[128 * 32];
    int tid  = threadIdx.x;
    int wave = tid >> 6, lane = tid & 63;
    int quad = lane >> 4, l16 = lane & 15;
    int m0 = blockIdx.x * 128, n0 = blockIdx.y * 128;
    int wr = (wave >> 1) * 64, wc = (wave & 1) * 64;

    f32x4 acc[4][4] = {};

    int cA = tid, cB = tid + 256;
    int rA0 = cA >> 2, kA0 = (cA & 3) * 8;
    int rB0 = cB >> 2, kB0 = (cB & 3) * 8;

    for (int k0 = 0; k0 < K; k0 += 32) {
        {
            int r = m0 + rA0; r = (r < M) ? r : (M - 1);
            ((uint4*)As)[cA] = *(const uint4*)(A + (size_t)r * K + k0 + kA0);
            r = m0 + rB0; r = (r < M) ? r : (M - 1);
            ((uint4*)As)[cB] = *(const uint4*)(A + (size_t)r * K + k0 + kB0);
            ((uint4*)Bs)[cA] = *(const uint4*)(Bt + (size_t)(n0 + rA0) * K + k0 + kA0);
            ((uint4*)Bs)[cB] = *(const uint4*)(Bt + (size_t)(n0 + rB0) * K + k0 + kB0);
        }
        __syncthreads();
        short8 af[4], bfr[4];
        #pragma unroll
        for (int i = 0; i < 4; ++i)
            af[i] = *(const short8*)(As + (wr + i * 16 + l16) * 32 + quad * 8);
        #pragma unroll
        for (int j = 0; j < 4; ++j)
            bfr[j] = *(const short8*)(Bs + (wc + j * 16 + l16) * 32 + quad * 8);
        #pragma unroll
        for (int i = 0; i < 4; ++i)
            #pragma unroll
            for (int j = 0; j < 4; ++j)
                acc[i][j] = __builtin_amdgcn_mfma_f32_16x16x32_bf16(
                    af[i], bfr[j], acc[i][j], 0, 0, 0);
        __syncthreads();
    }

    #pragma unroll
    for (int i = 0; i < 4; ++i) {
        #pragma unroll
        for (int j = 0; j < 4; ++j) {
            int col = n0 + wc + j * 16 + l16;
            float bsv = bias ? bias[col] : 0.0f;
            #pragma unroll
            for (int r = 0; r < 4; ++r) {
                int row = m0 + wr + i * 16 + quad * 4 + r;
                if (row < M) {
                    float v = acc[i][j][r] + bsv;
                    if (relu) v = fmaxf(v, 0.0f);
                    if (add)  v += add[(size_t)row * N + col];
                    if (Cf) Cf[(size_t)row * N + col] = v;
                    else    Cb[(size_t)row * N + col] = f2bf(v);
                }
            }
        }
    }
}

// ---------------------------------------------------------------------------
// Graph plumbing: degree count -> scan -> scatter (builds csr_src/csr_rid)
// ---------------------------------------------------------------------------
__global__ void count_kernel(const int* __restrict__ dst, int* __restrict__ deg, int E)
{
    int i = blockIdx.x * blockDim.x + threadIdx.x;
    if (i < E) atomicAdd(&deg[dst[i]], 1);
}

__global__ __launch_bounds__(256) void scan_kernel(
    const int* __restrict__ deg, int* __restrict__ offsets, int* __restrict__ cursor,
    float* __restrict__ logdeg, int n)
{
    __shared__ int part[256];
    int tid = threadIdx.x;
    int chunk = (n + 255) / 256;
    int lo = tid * chunk;
    int hi = min(lo + chunk, n);
    int s = 0;
    for (int i = lo; i < hi; ++i) s += deg[i];
    part[tid] = s;
    __syncthreads();
    for (int d = 1; d < 256; d <<= 1) {
        int v = part[tid];
        int u = (tid >= d) ? part[tid - d] : 0;
        __syncthreads();
        part[tid] = v + u;
        __syncthreads();
    }
    int run = (tid == 0) ? 0 : part[tid - 1];
    for (int i = lo; i < hi; ++i) {
        offsets[i] = run;
        cursor[i]  = run;
        logdeg[i] = logf((float)deg[i]);
        run += deg[i];
    }
    if (tid == 255) offsets[n] = run;
}

__global__ void scatter_kernel(const int* __restrict__ dst, const int* __restrict__ src,
                               const int* __restrict__ rid, int* __restrict__ cursor,
                               int* __restrict__ csr_src, int* __restrict__ csr_rid, int E)
{
    int i = blockIdx.x * blockDim.x + threadIdx.x;
    if (i < E) {
        int p = atomicAdd(&cursor[dst[i]], 1);
        csr_src[p] = src[i];
        csr_rid[p] = rid[i];
    }
}

// ---------------------------------------------------------------------------
// CSR edge attention + fused softmax, 8-edge windows.
// One wave per dst node (4/block). Lanes preload the window's 8 src/rid
// (coalesced) and broadcast via shfl -> 8 independent gathers in flight.
// ---------------------------------------------------------------------------
__global__ __launch_bounds__(256) void edge_score_csr_kernel(
    const unsigned short* __restrict__ proj,   // [N,768]: fh | ftl | fen
    const unsigned short* __restrict__ frel,   // [R,256] bf16
    const float* __restrict__ attn,
    const int* __restrict__ csr_src, const int* __restrict__ csr_rid,
    const int* __restrict__ offsets, const float* __restrict__ logdeg,
    float* __restrict__ csr_a, int n)
{
    int node = blockIdx.x * 4 + (threadIdx.x >> 6);
    if (node >= n) return;
    int tid = threadIdx.x & 63;
    int h = tid >> 3;
    int start = offsets[node], end = offsets[node + 1];
    float scale = logdeg[node] * (1.0f / 32.0f);
    float4 tv = bf4(*(const ushort4*)(proj + (size_t)node * 768 + 256 + tid * 4));
    float4 a4 = *(const float4*)(attn + tid * 4);
    bool leader = ((tid & 7) == 0);
    float denom = 0.f;

    int p = start;
    while (p < end) {
        int cnt = end - p; if (cnt > 8) cnt = 8;
        int pidx = p + (tid & 7); if (pidx >= end) pidx = end - 1;   // clamp: keep indices valid
        int s_l = csr_src[pidx];
        int r_l = csr_rid[pidx];
        #define ES_BODY(J)                                                            \
        {                                                                             \
            int s = __shfl(s_l, J);                                                   \
            int r = __shfl(r_l, J);                                                   \
            float4 hv = bf4(*(const ushort4*)(proj + (size_t)s * 768 + tid * 4));     \
            float4 rv = bf4(*(const ushort4*)(frel + (size_t)r * FDIM + tid * 4));    \
            float sum = 0.f, pp;                                                      \
            pp = hv.x * tv.x * rv.x; pp = (pp > 0.f) ? pp : 0.2f * pp; sum += pp * a4.x; \
            pp = hv.y * tv.y * rv.y; pp = (pp > 0.f) ? pp : 0.2f * pp; sum += pp * a4.y; \
            pp = hv.z * tv.z * rv.z; pp = (pp > 0.f) ? pp : 0.2f * pp; sum += pp * a4.z; \
            pp = hv.w * tv.w * rv.w; pp = (pp > 0.f) ? pp : 0.2f * pp; sum += pp * a4.w; \
            sum += __shfl_xor(sum, 1);                                                \
            sum += __shfl_xor(sum, 2);                                                \
            sum += __shfl_xor(sum, 4);                                                \
            if (leader) {                                                             \
                float ex = expf(sum * scale);                                         \
                csr_a[(size_t)(p + J) * NHEAD + h] = ex;                              \
                denom += ex;                                                          \
            }                                                                         \
        }
        if (cnt == 8) {
            ES_BODY(0) ES_BODY(1) ES_BODY(2) ES_BODY(3)
            ES_BODY(4) ES_BODY(5) ES_BODY(6) ES_BODY(7)
        } else {
            for (int j = 0; j < cnt; ++j) ES_BODY(j)
        }
        #undef ES_BODY
        p += cnt;
    }
    // normalize: denom lives in lanes h*8; broadcast to all lanes
    float dh = __shfl(denom, (tid & 7) << 3);
    for (int i = start * NHEAD + tid; i < end * NHEAD; i += 64)
        csr_a[i] = csr_a[i] / dh;
}

// ---------------------------------------------------------------------------
// One PPR hop (bf16), 8-edge windows, 4 nodes per 256-thread block.
// fout[n] = bf16(0.9*sum_in a*fin[src] + 0.1*feat0[n])
// ---------------------------------------------------------------------------
__global__ __launch_bounds__(256) void diffuse_kernel(
    const unsigned short* __restrict__ fin, int fin_stride,
    const unsigned short* __restrict__ feat0,
    const float* __restrict__ a, const int* __restrict__ csr_src,
    const int* __restrict__ offsets, unsigned short* __restrict__ fout, int n)
{
    int node = blockIdx.x * 4 + (threadIdx.x >> 6);
    if (node >= n) return;
    int tid = threadIdx.x & 63;
    int h = tid >> 3;
    int start = offsets[node], end = offsets[node + 1];
    float4 acc = make_float4(0.f, 0.f, 0.f, 0.f);

    int p = start;
    while (p < end) {
        int cnt = end - p; if (cnt > 8) cnt = 8;
        int pidx = p + (tid & 7); if (pidx >= end) pidx = end - 1;
        int   s_l = csr_src[pidx];
        float w_l = a[(size_t)p * NHEAD + tid];   // weights for edges p..p+7, all heads
        #define DF_BODY(J)                                                            \
        {                                                                             \
            int s = __shfl(s_l, J);                                                   \
            float w = __shfl(w_l, J * 8 + h);                                         \
            float4 f = bf4(*(const ushort4*)(fin + (size_t)s * fin_stride + tid * 4));\
            acc.x += w * f.x; acc.y += w * f.y; acc.z += w * f.z; acc.w += w * f.w;   \
        }
        if (cnt == 8) {
            DF_BODY(0) DF_BODY(1) DF_BODY(2) DF_BODY(3)
            DF_BODY(4) DF_BODY(5) DF_BODY(6) DF_BODY(7)
        } else {
            for (int j = 0; j < cnt; ++j) DF_BODY(j)
        }
        #undef DF_BODY
        p += cnt;
    }
    float4 f0 = bf4(*(const ushort4*)(feat0 + (size_t)node * 768 + tid * 4));
    ushort4 o;
    o.x = f2bf(0.9f * acc.x + 0.1f * f0.x);
    o.y = f2bf(0.9f * acc.y + 0.1f * f0.y);
    o.z = f2bf(0.9f * acc.z + 0.1f * f0.z);
    o.w = f2bf(0.9f * acc.w + 0.1f * f0.w);
    *(ushort4*)(fout + (size_t)node * FDIM + tid * 4) = o;
}

// ---------------------------------------------------------------------------
extern "C" void kernel_launch(void* const* d_in, const int* in_sizes, int n_in,
                              void* d_out, int out_size, void* d_ws, size_t ws_size,
                              hipStream_t stream)
{
    const float* ent_feat = (const float*)d_in[0];
    const float* rel_feat = (const float*)d_in[1];
    const float* W_head   = (const float*)d_in[2];
    const float* W_tail   = (const float*)d_in[3];
    const float* W_ent    = (const float*)d_in[4];
    const float* W_rel    = (const float*)d_in[5];
    const float* attn     = (const float*)d_in[6];
    const float* ln_ent_g = (const float*)d_in[7];
    const float* ln_ent_b = (const float*)d_in[8];
    const float* ln_rel_g = (const float*)d_in[9];
    const float* ln_rel_b = (const float*)d_in[10];
    const float* ln_ff_g  = (const float*)d_in[11];
    const float* ln_ff_b  = (const float*)d_in[12];
    const float* W1       = (const float*)d_in[13];
    const float* b1       = (const float*)d_in[14];
    const float* W2       = (const float*)d_in[15];
    const float* b2       = (const float*)d_in[16];
    const int*   src      = (const int*)d_in[17];
    const int*   dst      = (const int*)d_in[18];
    const int*   rid      = (const int*)d_in[19];
    float* out = (float*)d_out;

    // ---- workspace carve (bytes, 256-aligned) ----
    char* base = (char*)d_ws;
    auto carve = [&](size_t bytes) { char* p = base; base += (bytes + 255) & ~(size_t)255; return p; };
    unsigned short* xb    = (unsigned short*)carve((size_t)N_NODES * FDIM * 2);    // LN(ent) bf16
    unsigned short* projb = (unsigned short*)carve((size_t)N_NODES * 768 * 2);     // fh|ftl|fen bf16
    unsigned short* rlnb  = (unsigned short*)carve((size_t)N_REL * FDIM * 2);
    unsigned short* frelb = (unsigned short*)carve((size_t)N_REL * FDIM * 2);
    unsigned short* WtP   = (unsigned short*)carve((size_t)768 * FDIM * 2);        // head|tail|ent ^T
    unsigned short* WtR   = (unsigned short*)carve((size_t)FDIM * FDIM * 2);
    unsigned short* W1t   = (unsigned short*)carve((size_t)1024 * FDIM * 2);
    unsigned short* W2t   = (unsigned short*)carve((size_t)FDIM * 1024 * 2);
    unsigned short* hb0   = (unsigned short*)carve((size_t)N_NODES * FDIM * 2);
    unsigned short* hb1   = (unsigned short*)carve((size_t)N_NODES * FDIM * 2);
    unsigned short* yb    = (unsigned short*)carve((size_t)N_NODES * FDIM * 2);
    unsigned short* t1b   = (unsigned short*)carve((size_t)N_NODES * 1024 * 2);
    float* rst     = (float*)carve((size_t)N_NODES * FDIM * 4);
    float* csr_a   = (float*)carve((size_t)N_EDGES * NHEAD * 4);
    int*   csr_src = (int*)carve((size_t)N_EDGES * 4);
    int*   csr_rid = (int*)carve((size_t)N_EDGES * 4);
    int*   deg     = (int*)carve((size_t)N_NODES * 4);
    float* logdeg  = (float*)carve((size_t)N_NODES * 4);
    int*   offsets = (int*)carve((size_t)(N_NODES + 1) * 4);
    int*   cursor  = (int*)carve((size_t)N_NODES * 4);

    hipMemsetAsync(deg, 0, (size_t)N_NODES * 4, stream);

    // LN -> bf16
    ln_bf16_kernel<<<N_NODES, 64, 0, stream>>>(ent_feat, ln_ent_g, ln_ent_b, xb, N_NODES);
    ln_bf16_kernel<<<N_REL, 64, 0, stream>>>(rel_feat, ln_rel_g, ln_rel_b, rlnb, N_REL);

    // weight transposes (fp32 [K,N] -> bf16 [N,K]); WtP rows = [head | tail | ent]
    transpose_bf16_kernel<<<(65536 + 255) / 256, 256, 0, stream>>>(W_head, WtP,               FDIM, FDIM);
    transpose_bf16_kernel<<<(65536 + 255) / 256, 256, 0, stream>>>(W_tail, WtP + 256 * FDIM,  FDIM, FDIM);
    transpose_bf16_kernel<<<(65536 + 255) / 256, 256, 0, stream>>>(W_ent,  WtP + 512 * FDIM,  FDIM, FDIM);
    transpose_bf16_kernel<<<(65536 + 255) / 256, 256, 0, stream>>>(W_rel,  WtR, FDIM, FDIM);
    transpose_bf16_kernel<<<(262144 + 255) / 256, 256, 0, stream>>>(W1, W1t, FDIM, 1024);
    transpose_bf16_kernel<<<(262144 + 255) / 256, 256, 0, stream>>>(W2, W2t, 1024, FDIM);

    // fused projection GEMM: proj[N,768] = xb @ [Wh|Wt|We]  (bf16 out)
    dim3 gproj((N_NODES + 127) / 128, 768 / 128);
    mfma_gemm_bt<<<gproj, 256, 0, stream>>>(xb, WtP, nullptr, nullptr, nullptr, projb,
                                            N_NODES, FDIM, 768, 0);
    dim3 grel(1, FDIM / 128);
    mfma_gemm_bt<<<grel, 256, 0, stream>>>(rlnb, WtR, nullptr, nullptr, nullptr, frelb,
                                           N_REL, FDIM, FDIM, 0);

    // CSR build
    count_kernel<<<(N_EDGES + 255) / 256, 256, 0, stream>>>(dst, deg, N_EDGES);
    scan_kernel<<<1, 256, 0, stream>>>(deg, offsets, cursor, logdeg, N_NODES);
    scatter_kernel<<<(N_EDGES + 255) / 256, 256, 0, stream>>>(dst, src, rid, cursor,
                                                              csr_src, csr_rid, N_EDGES);

    // attention + fused softmax (normalized a in CSR order)
    edge_score_csr_kernel<<<(N_NODES + 3) / 4, 256, 0, stream>>>(
        projb, frelb, attn, csr_src, csr_rid, offsets, logdeg, csr_a, N_NODES);

    // 5-hop PPR diffusion (bf16): fen(proj+512) -> hb0 -> hb1 -> hb0 -> hb1 -> hb0
    const unsigned short* fen = projb + 512;
    int gdif = (N_NODES + 3) / 4;
    diffuse_kernel<<<gdif, 256, 0, stream>>>(fen, 768, fen, csr_a, csr_src, offsets, hb0, N_NODES);
    diffuse_kernel<<<gdif, 256, 0, stream>>>(hb0, FDIM, fen, csr_a, csr_src, offsets, hb1, N_NODES);
    diffuse_kernel<<<gdif, 256, 0, stream>>>(hb1, FDIM, fen, csr_a, csr_src, offsets, hb0, N_NODES);
    diffuse_kernel<<<gdif, 256, 0, stream>>>(hb0, FDIM, fen, csr_a, csr_src, offsets, hb1, N_NODES);
    diffuse_kernel<<<gdif, 256, 0, stream>>>(hb1, FDIM, fen, csr_a, csr_src, offsets, hb0, N_NODES);

    // residual + pre-LN
    rst_ln_kernel<<<N_NODES, 64, 0, stream>>>(hb0, ent_feat, ln_ff_g, ln_ff_b, rst, yb);

    // FFN: t1 = relu(y@W1 + b1) [bf16]; out = t1@W2 + b2 + rst [fp32]
    dim3 gff1((N_NODES + 127) / 128, 1024 / 128);
    mfma_gemm_bt<<<gff1, 256, 0, stream>>>(yb, W1t, b1, nullptr, nullptr, t1b,
                                           N_NODES, FDIM, 1024, 1);
    dim3 gff2((N_NODES + 127) / 128, FDIM / 128);
    mfma_gemm_bt<<<gff2, 256, 0, stream>>>(t1b, W2t, b2, rst, out, nullptr,
                                           N_NODES, 1024, FDIM, 0);
}